// Round 3
// baseline (1405.901 us; speedup 1.0000x reference)
//
#include <hip/hip_runtime.h>

// ---------------------------------------------------------------------------
// RingLlamaAttention on MI355X (gfx950)
// cast f32->bf16 | rope tables | Q,K gemms + V gemm TRANSPOSED (vT[f][t]) |
// rope apply (Q pre-scaled by scale*log2e) | flash attention (gload_lds-staged
// K and vT with XOR-swizzled sources, exp2-domain softmax, defer-max) |
// O gemm -> f32 out.   All GEMMs: XCD-bijective block swizzle (T1).
// Shapes: B=2, S=4096, s_local=1024, H=4096, nh=32, hd=128, K=4096
// ---------------------------------------------------------------------------

using bf16x8 = __attribute__((ext_vector_type(8))) short;
using f32x4  = __attribute__((ext_vector_type(4))) float;

__device__ inline unsigned short f32_to_bf16_bits(float f) {
  unsigned int u = __float_as_uint(f);
  u += 0x7FFFu + ((u >> 16) & 1u);   // round-to-nearest-even
  return (unsigned short)(u >> 16);
}
__device__ inline float bf16_bits_to_f32(unsigned short h) {
  return __uint_as_float(((unsigned int)h) << 16);
}

// async global->LDS, 16B per lane (dest must be wave-uniform base + lane*16)
__device__ __forceinline__ void load_lds16(const unsigned short* g, unsigned short* l) {
  __builtin_amdgcn_global_load_lds(
      (const __attribute__((address_space(1))) void*)g,
      (__attribute__((address_space(3))) void*)l, 16, 0, 0);
}

// ---- elementwise f32 -> bf16 cast ----
__global__ void cast_f32_bf16(const float* __restrict__ in,
                              unsigned short* __restrict__ out, long n4) {
  long i = (long)blockIdx.x * blockDim.x + threadIdx.x;
  long stride = (long)gridDim.x * blockDim.x;
  for (; i < n4; i += stride) {
    float4 v = reinterpret_cast<const float4*>(in)[i];
    ushort4 o;
    o.x = f32_to_bf16_bits(v.x);
    o.y = f32_to_bf16_bits(v.y);
    o.z = f32_to_bf16_bits(v.z);
    o.w = f32_to_bf16_bits(v.w);
    reinterpret_cast<ushort4*>(out)[i] = o;
  }
}

// ---- RoPE cos/sin tables: pos 0..4095 x freq 0..63, fp32 ----
__global__ void rope_tables(float* __restrict__ cos_t, float* __restrict__ sin_t) {
  int idx = blockIdx.x * 256 + threadIdx.x;
  if (idx >= 4096 * 64) return;
  int p = idx >> 6, i = idx & 63;
  float inv = __expf(-(float)i * (9.210340371976184f / 64.0f));  // theta^(-i/64)
  float f = (float)p * inv;
  cos_t[idx] = cosf(f);
  sin_t[idx] = sinf(f);
}

// ---- RoPE apply in-place, pos = tok & pos_mask, output scaled by gain ----
__global__ void rope_apply(unsigned short* __restrict__ buf,
                           const float* __restrict__ cos_t,
                           const float* __restrict__ sin_t,
                           long total, int pos_mask, float gain) {
  long idx = (long)blockIdx.x * 256 + threadIdx.x;
  if (idx >= total) return;
  long tok = idx >> 11;            // 2048 (head,freq) pairs per token
  int rem  = (int)(idx & 2047);
  int head = rem >> 6, i = rem & 63;
  int pos  = (int)(tok & (long)pos_mask);
  float c = cos_t[pos * 64 + i], s = sin_t[pos * 64 + i];
  long base = tok * 4096 + head * 128 + i;
  float x1 = bf16_bits_to_f32(buf[base]);
  float x2 = bf16_bits_to_f32(buf[base + 64]);
  buf[base]      = f32_to_bf16_bits((x1 * c - x2 * s) * gain);
  buf[base + 64] = f32_to_bf16_bits((x2 * c + x1 * s) * gain);
}

// ---- GEMM C[M,N] = A[M,K]*B[N,K]^T, K=4096, bf16 in, f32 acc ----
// 128x128 tile, 4 waves (2x2 of 64x64), BK=32, global_load_lds staging (m97),
// flat grid + XCD-bijective swizzle (T1; gridDim.x % 8 == 0 required).
__device__ inline void storeC(float* p, float v) { *p = v; }
__device__ inline void storeC(unsigned short* p, float v) { *p = f32_to_bf16_bits(v); }

template <typename OUT_T>
__global__ __launch_bounds__(256) void gemm_bt(const unsigned short* __restrict__ A,
                                               const unsigned short* __restrict__ B,
                                               OUT_T* __restrict__ C,
                                               long Astride_z, long Cstride_z, int N,
                                               int nbn, int nbm) {
  __shared__ unsigned short As[128 * 32];
  __shared__ unsigned short Bs[128 * 32];
  const int tid = threadIdx.x;
  // XCD swizzle: consecutive swz ids land on the same XCD, sharing A/B panels in L2
  const int nwg = gridDim.x;
  const int id = blockIdx.x;
  const int swz = (id & 7) * (nwg >> 3) + (id >> 3);
  const int per_z = nbn * nbm;
  const int bz = swz / per_z;
  const int rr = swz - bz * per_z;
  const int bm = rr / nbn;
  const int bn = rr - bm * nbn;

  const unsigned short* Ab = A + (long)bz * Astride_z + (long)bm * 128 * 4096;
  const unsigned short* Bb = B + (long)bn * 128 * 4096;
  OUT_T* Cb = C + (long)bz * Cstride_z + (long)bm * 128 * N + (long)bn * 128;

  const int lane = tid & 63;
  const int w = tid >> 6;
  const int wr = (w >> 1) * 64, wc = (w & 1) * 64;
  const int fr = lane & 15, fg = lane >> 4;

  f32x4 acc[4][4] = {};

  const int c0 = tid, c1 = tid + 256;
  const int rA0 = c0 >> 2, kc0 = c0 & 3;
  const int rA1 = c1 >> 2, kc1 = c1 & 3;

  for (int k0 = 0; k0 < 4096; k0 += 32) {
    load_lds16(Ab + (long)rA0 * 4096 + k0 + kc0 * 8, As + c0 * 8);
    load_lds16(Ab + (long)rA1 * 4096 + k0 + kc1 * 8, As + c1 * 8);
    load_lds16(Bb + (long)rA0 * 4096 + k0 + kc0 * 8, Bs + c0 * 8);
    load_lds16(Bb + (long)rA1 * 4096 + k0 + kc1 * 8, Bs + c1 * 8);
    __syncthreads();   // compiler drains vmcnt before barrier
    bf16x8 af[4], bfv[4];
#pragma unroll
    for (int m = 0; m < 4; m++)
      af[m] = *reinterpret_cast<const bf16x8*>(As + (wr + m * 16 + fr) * 32 + fg * 8);
#pragma unroll
    for (int n = 0; n < 4; n++)
      bfv[n] = *reinterpret_cast<const bf16x8*>(Bs + (wc + n * 16 + fr) * 32 + fg * 8);
#pragma unroll
    for (int m = 0; m < 4; m++)
#pragma unroll
      for (int n = 0; n < 4; n++)
        acc[m][n] = __builtin_amdgcn_mfma_f32_16x16x32_bf16(af[m], bfv[n], acc[m][n], 0, 0, 0);
    __syncthreads();
  }
  // D col = lane&15, row = (lane>>4)*4 + reg  [m89-verified]
#pragma unroll
  for (int m = 0; m < 4; m++)
#pragma unroll
    for (int n = 0; n < 4; n++)
#pragma unroll
      for (int r = 0; r < 4; r++) {
        int row = wr + m * 16 + fg * 4 + r;
        int col = wc + n * 16 + fr;
        storeC(Cb + (long)row * N + col, acc[m][n][r]);
      }
}

// ---- flash attention: grid flat 1024 = (16 qtiles x 32 heads x 2 batch) ----
// 64 q rows/block, 4 waves x 16 rows; kv tiles of 64 keys.
// K staged [key][16 chunks], chunk slot = L ^ (key&15)   (gload_lds, src-swizzled)
// vT staged [feat][8 chunks], chunk slot = L ^ (feat&7)  (gload_lds, src-swizzled)
// Softmax in exp2 domain (Q pre-scaled by scale*log2e at rope), defer-max T13.
__global__ __launch_bounds__(256) void attn_fwd(const unsigned short* __restrict__ qb,
                                                const unsigned short* __restrict__ kb,
                                                const unsigned short* __restrict__ vT,
                                                unsigned short* __restrict__ ob) {
  __shared__ unsigned short Ks[64 * 128];
  __shared__ unsigned short Vl[128 * 64];
  __shared__ unsigned short Ps[4][16 * 72];

  const int qt = blockIdx.x, h = blockIdx.y, b = blockIdx.z;
  const int tid = threadIdx.x, w = tid >> 6, lane = tid & 63;
  const int fr = lane & 15, fg = lane >> 4;

  const unsigned short* kbase = kb + (long)b * 4096 * 4096 + h * 128;
  const unsigned short* vbase = vT + (long)h * 128 * 8192 + (long)b * 4096;

  // Q fragments (A-operand): row=fr, k=fg*8+c*32; pre-scaled at rope time
  bf16x8 qf[4];
  {
    const unsigned short* qptr =
        qb + ((long)b * 1024 + qt * 64 + w * 16 + fr) * 4096 + h * 128 + fg * 8;
#pragma unroll
    for (int c = 0; c < 4; c++) qf[c] = *reinterpret_cast<const bf16x8*>(qptr + c * 32);
  }

  f32x4 outa[8] = {};
  float m_run[4], l_run[4];
#pragma unroll
  for (int r = 0; r < 4; r++) { m_run[r] = -1e30f; l_run[r] = 0.0f; }

  for (int kv0 = 0; kv0 < 4096; kv0 += 64) {
    __syncthreads();  // all waves done reading previous tile
    // K tile: 64x128, lane-linear LDS; global src chunk = slot ^ (key&15)
#pragma unroll
    for (int i = 0; i < 4; i++) {
      int c = tid + 256 * i;
      int key = c >> 4, s = c & 15;
      int Lg = s ^ (key & 15);
      load_lds16(kbase + (long)(kv0 + key) * 4096 + Lg * 8, Ks + c * 8);
    }
    // vT tile: 128 feats x 64 keys; global src chunk = slot ^ (feat&7)
#pragma unroll
    for (int i = 0; i < 4; i++) {
      int c = tid + 256 * i;
      int f = c >> 3, s = c & 7;
      int Lg = s ^ (f & 7);
      load_lds16(vbase + (long)f * 8192 + kv0 + Lg * 8, Vl + c * 8);
    }
    __syncthreads();  // vmcnt drained by compiler before barrier

    // S = Q K^T : 4 key-subtiles of 16; read swizzle: slot = (cc*4+fg) ^ fr
    f32x4 sacc[4];
#pragma unroll
    for (int ks = 0; ks < 4; ks++) {
      f32x4 a = {0.f, 0.f, 0.f, 0.f};
#pragma unroll
      for (int cc = 0; cc < 4; cc++) {
        bf16x8 kf = *reinterpret_cast<const bf16x8*>(
            &Ks[(ks * 16 + fr) * 128 + (((cc * 4 + fg) ^ fr) & 15) * 8]);
        a = __builtin_amdgcn_mfma_f32_16x16x32_bf16(qf[cc], kf, a, 0, 0, 0);
      }
      sacc[ks] = a;
    }

    // online softmax, exp2 domain; row = fg*4+r; reduce over 16 fr-lanes
    float mx4[4];
#pragma unroll
    for (int r = 0; r < 4; r++) {
      float mx = fmaxf(fmaxf(sacc[0][r], sacc[1][r]), fmaxf(sacc[2][r], sacc[3][r]));
      mx = fmaxf(mx, __shfl_xor(mx, 1));
      mx = fmaxf(mx, __shfl_xor(mx, 2));
      mx = fmaxf(mx, __shfl_xor(mx, 4));
      mx = fmaxf(mx, __shfl_xor(mx, 8));
      mx4[r] = mx;
    }
    int need = 0;
#pragma unroll
    for (int r = 0; r < 4; r++) need |= (mx4[r] > m_run[r] + 11.5f) ? 1 : 0;
    if (__any(need)) {  // rescale pass (skipped most tiles: defer-max, T13)
#pragma unroll
      for (int r = 0; r < 4; r++) {
        float mnew = fmaxf(m_run[r], mx4[r]);
        float ef = exp2f(m_run[r] - mnew);
        l_run[r] *= ef;
        m_run[r] = mnew;
#pragma unroll
        for (int ds = 0; ds < 8; ds++) outa[ds][r] *= ef;
      }
    }
    float p[4][4];
#pragma unroll
    for (int r = 0; r < 4; r++) {
      float sum = 0.f;
#pragma unroll
      for (int ks = 0; ks < 4; ks++) {
        float pv = exp2f(sacc[ks][r] - m_run[r]);   // bounded by 2^11.5
        p[ks][r] = pv;
        sum += pv;
      }
      sum += __shfl_xor(sum, 1);
      sum += __shfl_xor(sum, 2);
      sum += __shfl_xor(sum, 4);
      sum += __shfl_xor(sum, 8);
      l_run[r] += sum;
    }

    // P -> LDS (wave-private), layout [q][key] for A-operand reads
#pragma unroll
    for (int r = 0; r < 4; r++)
#pragma unroll
      for (int ks = 0; ks < 4; ks++)
        Ps[w][(fg * 4 + r) * 72 + ks * 16 + fr] = f32_to_bf16_bits(p[ks][r]);

    // O += P V : B-operand from Vl, slot = (c2*4+fg) ^ (feat&7), feat=ds*16+fr
#pragma unroll
    for (int c2 = 0; c2 < 2; c2++) {
      bf16x8 pf = *reinterpret_cast<const bf16x8*>(&Ps[w][fr * 72 + c2 * 32 + fg * 8]);
#pragma unroll
      for (int ds = 0; ds < 8; ds++) {
        int feat = ds * 16 + fr;
        int pch = ((c2 * 4 + fg) ^ (feat & 7)) & 7;
        bf16x8 vf = *reinterpret_cast<const bf16x8*>(&Vl[feat * 64 + pch * 8]);
        outa[ds] = __builtin_amdgcn_mfma_f32_16x16x32_bf16(pf, vf, outa[ds], 0, 0, 0);
      }
    }
  }

  // normalize + store bf16 [tok][h*128+d]
#pragma unroll
  for (int r = 0; r < 4; r++) {
    float inv = 1.0f / l_run[r];
    unsigned short* op =
        ob + ((long)b * 1024 + qt * 64 + w * 16 + fg * 4 + r) * 4096 + h * 128;
#pragma unroll
    for (int ds = 0; ds < 8; ds++) op[ds * 16 + fr] = f32_to_bf16_bits(outa[ds][r] * inv);
  }
}

// ---------------------------------------------------------------------------
extern "C" void kernel_launch(void* const* d_in, const int* in_sizes, int n_in,
                              void* d_out, int out_size, void* d_ws, size_t ws_size,
                              hipStream_t stream) {
  const float* hs = (const float*)d_in[0];
  const float* wq = (const float*)d_in[1];
  const float* wk = (const float*)d_in[2];
  const float* wv = (const float*)d_in[3];
  const float* wo = (const float*)d_in[4];
  float* out = (float*)d_out;

  const long hsN = 2L * 4096 * 4096;
  const long wN  = 4096L * 4096;

  unsigned short* hs_b = (unsigned short*)d_ws;
  unsigned short* wq_b = hs_b + hsN;
  unsigned short* wk_b = wq_b + wN;
  unsigned short* wv_b = wk_b + wN;
  unsigned short* wo_b = wv_b + wN;
  unsigned short* q_b  = wo_b + wN;             // 2048 x 4096
  unsigned short* k_b  = q_b + 2048L * 4096;    // 8192 x 4096 (natural [tok][feat])
  unsigned short* vT_b = k_b + 8192L * 4096;    // 4096 x 8192 (TRANSPOSED [feat][tok])
  unsigned short* at_b = vT_b + 8192L * 4096;   // 2048 x 4096
  float* cos_t = (float*)(at_b + 2048L * 4096);
  float* sin_t = cos_t + 4096 * 64;

  cast_f32_bf16<<<dim3(4096), dim3(256), 0, stream>>>(hs, hs_b, hsN / 4);
  cast_f32_bf16<<<dim3(2048), dim3(256), 0, stream>>>(wq, wq_b, wN / 4);
  cast_f32_bf16<<<dim3(2048), dim3(256), 0, stream>>>(wk, wk_b, wN / 4);
  cast_f32_bf16<<<dim3(2048), dim3(256), 0, stream>>>(wv, wv_b, wN / 4);
  cast_f32_bf16<<<dim3(2048), dim3(256), 0, stream>>>(wo, wo_b, wN / 4);

  rope_tables<<<dim3(1024), dim3(256), 0, stream>>>(cos_t, sin_t);

  // Q[tok][feat] (2 batches of 1024 rows)
  gemm_bt<unsigned short><<<dim3(512), dim3(256), 0, stream>>>(
      hs_b, wq_b, q_b, 4096L * 4096, 1024L * 4096, 4096, 32, 8);
  // K[tok][feat]
  gemm_bt<unsigned short><<<dim3(2048), dim3(256), 0, stream>>>(
      hs_b, wk_b, k_b, 4096L * 4096, 4096L * 4096, 4096, 32, 32);
  // V TRANSPOSED: vT[feat][tok] = sum_k Wv[feat][k] * hs[tok][k]
  gemm_bt<unsigned short><<<dim3(2048), dim3(256), 0, stream>>>(
      wv_b, hs_b, vT_b, 0L, 0L, 8192, 64, 32);

  // RoPE; Q output folded with (1/sqrt(128))*log2(e) for exp2-domain softmax
  const float qgain = 0.08838834764831845f * 1.4426950408889634f;
  rope_apply<<<dim3(16384), dim3(256), 0, stream>>>(q_b, cos_t, sin_t, 2048L * 2048, 1023, qgain);
  rope_apply<<<dim3(65536), dim3(256), 0, stream>>>(k_b, cos_t, sin_t, 8192L * 2048, 4095, 1.0f);

  attn_fwd<<<dim3(16, 32, 2), dim3(256), 0, stream>>>(q_b, k_b, vT_b, at_b);

  gemm_bt<float><<<dim3(512), dim3(256), 0, stream>>>(
      at_b, wo_b, out, 0L, 0L, 4096, 32, 16);
}

// Round 5
// 1124.498 us; speedup vs baseline: 1.2502x; 1.2502x over previous
//
#include <hip/hip_runtime.h>

// ---------------------------------------------------------------------------
// RingLlamaAttention on MI355X (gfx950)
// cast f32->bf16 | rope tables | Q gemm (128^2) + K,vT gemms (256^2 pipelined) |
// rope apply | flash attention (gload_lds staged, exp2 softmax, defer-max) |
// O gemm (128^2) -> f32 out
// Shapes: B=2, S=4096, s_local=1024, H=4096, nh=32, hd=128, K=4096
// ---------------------------------------------------------------------------

using bf16x8 = __attribute__((ext_vector_type(8))) short;
using f32x4  = __attribute__((ext_vector_type(4))) float;

__device__ inline unsigned short f32_to_bf16_bits(float f) {
  unsigned int u = __float_as_uint(f);
  u += 0x7FFFu + ((u >> 16) & 1u);   // round-to-nearest-even
  return (unsigned short)(u >> 16);
}
__device__ inline float bf16_bits_to_f32(unsigned short h) {
  return __uint_as_float(((unsigned int)h) << 16);
}

// async global->LDS, 16B per lane (dest must be wave-uniform base + lane*16)
__device__ __forceinline__ void load_lds16(const unsigned short* g, unsigned short* l) {
  __builtin_amdgcn_global_load_lds(
      (const __attribute__((address_space(1))) void*)g,
      (__attribute__((address_space(3))) void*)l, 16, 0, 0);
}

// ---- elementwise f32 -> bf16 cast ----
__global__ void cast_f32_bf16(const float* __restrict__ in,
                              unsigned short* __restrict__ out, long n4) {
  long i = (long)blockIdx.x * blockDim.x + threadIdx.x;
  long stride = (long)gridDim.x * blockDim.x;
  for (; i < n4; i += stride) {
    float4 v = reinterpret_cast<const float4*>(in)[i];
    ushort4 o;
    o.x = f32_to_bf16_bits(v.x);
    o.y = f32_to_bf16_bits(v.y);
    o.z = f32_to_bf16_bits(v.z);
    o.w = f32_to_bf16_bits(v.w);
    reinterpret_cast<ushort4*>(out)[i] = o;
  }
}

// ---- RoPE cos/sin tables ----
__global__ void rope_tables(float* __restrict__ cos_t, float* __restrict__ sin_t) {
  int idx = blockIdx.x * 256 + threadIdx.x;
  if (idx >= 4096 * 64) return;
  int p = idx >> 6, i = idx & 63;
  float inv = __expf(-(float)i * (9.210340371976184f / 64.0f));  // theta^(-i/64)
  float f = (float)p * inv;
  cos_t[idx] = cosf(f);
  sin_t[idx] = sinf(f);
}

// ---- RoPE apply in-place, pos = tok & pos_mask, output scaled by gain ----
__global__ void rope_apply(unsigned short* __restrict__ buf,
                           const float* __restrict__ cos_t,
                           const float* __restrict__ sin_t,
                           long total, int pos_mask, float gain) {
  long idx = (long)blockIdx.x * 256 + threadIdx.x;
  if (idx >= total) return;
  long tok = idx >> 11;
  int rem  = (int)(idx & 2047);
  int head = rem >> 6, i = rem & 63;
  int pos  = (int)(tok & (long)pos_mask);
  float c = cos_t[pos * 64 + i], s = sin_t[pos * 64 + i];
  long base = tok * 4096 + head * 128 + i;
  float x1 = bf16_bits_to_f32(buf[base]);
  float x2 = bf16_bits_to_f32(buf[base + 64]);
  buf[base]      = f32_to_bf16_bits((x1 * c - x2 * s) * gain);
  buf[base + 64] = f32_to_bf16_bits((x2 * c + x1 * s) * gain);
}

__device__ inline void storeC(float* p, float v) { *p = v; }
__device__ inline void storeC(unsigned short* p, float v) { *p = f32_to_bf16_bits(v); }

// ---- 128^2 GEMM (m97 structure): used for the small Q / O projections ----
template <typename OUT_T>
__global__ __launch_bounds__(256) void gemm_bt(const unsigned short* __restrict__ A,
                                               const unsigned short* __restrict__ B,
                                               OUT_T* __restrict__ C,
                                               long Astride_z, long Cstride_z, int N) {
  __shared__ unsigned short As[128 * 32];
  __shared__ unsigned short Bs[128 * 32];
  const int tid = threadIdx.x;
  const int bn = blockIdx.x, bm = blockIdx.y, bz = blockIdx.z;
  const unsigned short* Ab = A + (long)bz * Astride_z + (long)bm * 128 * 4096;
  const unsigned short* Bb = B + (long)bn * 128 * 4096;
  OUT_T* Cb = C + (long)bz * Cstride_z + (long)bm * 128 * N + (long)bn * 128;

  const int lane = tid & 63;
  const int w = tid >> 6;
  const int wr = (w >> 1) * 64, wc = (w & 1) * 64;
  const int fr = lane & 15, fg = lane >> 4;

  f32x4 acc[4][4] = {};

  const int c0 = tid, c1 = tid + 256;
  const int rA0 = c0 >> 2, kc0 = c0 & 3;
  const int rA1 = c1 >> 2, kc1 = c1 & 3;

  for (int k0 = 0; k0 < 4096; k0 += 32) {
    load_lds16(Ab + (long)rA0 * 4096 + k0 + kc0 * 8, As + c0 * 8);
    load_lds16(Ab + (long)rA1 * 4096 + k0 + kc1 * 8, As + c1 * 8);
    load_lds16(Bb + (long)rA0 * 4096 + k0 + kc0 * 8, Bs + c0 * 8);
    load_lds16(Bb + (long)rA1 * 4096 + k0 + kc1 * 8, Bs + c1 * 8);
    __syncthreads();
    bf16x8 af[4], bfv[4];
#pragma unroll
    for (int m = 0; m < 4; m++)
      af[m] = *reinterpret_cast<const bf16x8*>(As + (wr + m * 16 + fr) * 32 + fg * 8);
#pragma unroll
    for (int n = 0; n < 4; n++)
      bfv[n] = *reinterpret_cast<const bf16x8*>(Bs + (wc + n * 16 + fr) * 32 + fg * 8);
#pragma unroll
    for (int m = 0; m < 4; m++)
#pragma unroll
      for (int n = 0; n < 4; n++)
        acc[m][n] = __builtin_amdgcn_mfma_f32_16x16x32_bf16(af[m], bfv[n], acc[m][n], 0, 0, 0);
    __syncthreads();
  }
#pragma unroll
  for (int m = 0; m < 4; m++)
#pragma unroll
    for (int n = 0; n < 4; n++)
#pragma unroll
      for (int r = 0; r < 4; r++) {
        int row = wr + m * 16 + fg * 4 + r;
        int col = wc + n * 16 + fr;
        storeC(Cb + (long)row * N + col, acc[m][n][r]);
      }
}

// ---- 256^2 depth-2 pipelined GEMM: C[M,N] = A[M,K]*B[N,K]^T, K=4096 ----
// 512 thr (8 waves, 2x4 of 128x64), BK=64.
// LDS 128 KiB: {A,B} x {half0,half1} x {parity0,parity1}, 16 KB each.
// Half layout: [128 rows][8 slots x 16B]; LDS(row,slot) holds global chunk
// slot^(row&7)  (G4 8-way bank-spread; staged via pre-swizzled global source,
// lane-linear LDS dest per m104/m173; read slot = chunk^(row&7) — involution).
// Tile t reads parity t&1 and stages tile t+2 into the SAME parity, but each
// region (A / B) only after an lgkmcnt(0)+barrier following its last read.
// vmcnt(8) once per tile => previous tile's 8 loads landed (T4 counted vmcnt).

#define STG2(Gb, Lb, h, kc)                                                    \
  load_lds16((Gb) + (long)((h) * 128 + srow) * 4096 + sslot * 8 + (kc),        \
             (Lb) + tid * 8);                                                  \
  load_lds16((Gb) + (long)((h) * 128 + 64 + srow) * 4096 + sslot * 8 + (kc),   \
             (Lb) + 4096 + tid * 8);

#define MFMAQ(MH, NH)                                                          \
  _Pragma("unroll") for (int mi = 0; mi < 4; ++mi)                             \
    _Pragma("unroll") for (int ni = 0; ni < 2; ++ni)                           \
      _Pragma("unroll") for (int kk = 0; kk < 2; ++kk)                         \
        acc[(MH) * 4 + mi][(NH) * 2 + ni] =                                    \
            __builtin_amdgcn_mfma_f32_16x16x32_bf16(                           \
                a[mi][kk], b[(NH) * 2 + ni][kk],                               \
                acc[(MH) * 4 + mi][(NH) * 2 + ni], 0, 0, 0);

// MODE 0: steady (stage t+2, vmcnt(8)); 1: tile 62 (no stage, vmcnt(0));
// MODE 2: tile 63 (no stage, no vmcnt)
#define TILE(P, KC, MODE)                                                      \
  {                                                                            \
    const unsigned short* Ar = lds + wm * 16384 + (P) * 8192;                  \
    const unsigned short* Br =                                                 \
        lds + 32768 + (wn >> 1) * 16384 + (P) * 8192 + (wn & 1) * 4096;        \
    _Pragma("unroll") for (int mf = 0; mf < 4; ++mf) {                         \
      a[mf][0] = *reinterpret_cast<const bf16x8*>(Ar + mf * 1024 + ao0);       \
      a[mf][1] = *reinterpret_cast<const bf16x8*>(Ar + mf * 1024 + ao1);       \
    }                                                                          \
    _Pragma("unroll") for (int nf = 0; nf < 2; ++nf) {                         \
      b[nf][0] = *reinterpret_cast<const bf16x8*>(Br + nf * 1024 + ao0);       \
      b[nf][1] = *reinterpret_cast<const bf16x8*>(Br + nf * 1024 + ao1);       \
    }                                                                          \
    __builtin_amdgcn_s_setprio(1);                                             \
    MFMAQ(0, 0);                                                               \
    __builtin_amdgcn_s_setprio(0);                                             \
    _Pragma("unroll") for (int nf = 2; nf < 4; ++nf) {                         \
      b[nf][0] = *reinterpret_cast<const bf16x8*>(Br + nf * 1024 + ao0);       \
      b[nf][1] = *reinterpret_cast<const bf16x8*>(Br + nf * 1024 + ao1);       \
    }                                                                          \
    __builtin_amdgcn_s_setprio(1);                                             \
    MFMAQ(0, 1);                                                               \
    __builtin_amdgcn_s_setprio(0);                                             \
    asm volatile("s_waitcnt lgkmcnt(0)" ::: "memory");                         \
    asm volatile("s_barrier" ::: "memory"); /* B[.][P] fully read */           \
    if ((MODE) == 0) {                                                         \
      STG2(Bg, lds + 32768 + (P) * 8192, 0, KC);                               \
      STG2(Bg, lds + 49152 + (P) * 8192, 1, KC);                               \
    }                                                                          \
    _Pragma("unroll") for (int mf = 0; mf < 4; ++mf) {                         \
      a[mf][0] = *reinterpret_cast<const bf16x8*>(Ar + (4 + mf) * 1024 + ao0); \
      a[mf][1] = *reinterpret_cast<const bf16x8*>(Ar + (4 + mf) * 1024 + ao1); \
    }                                                                          \
    __builtin_amdgcn_s_setprio(1);                                             \
    MFMAQ(1, 0);                                                               \
    __builtin_amdgcn_s_setprio(0);                                             \
    asm volatile("s_waitcnt lgkmcnt(0)" ::: "memory");                         \
    asm volatile("s_barrier" ::: "memory"); /* A[.][P] fully read */           \
    if ((MODE) == 0) {                                                         \
      STG2(Ag, lds + (P) * 8192, 0, KC);                                       \
      STG2(Ag, lds + 16384 + (P) * 8192, 1, KC);                               \
    }                                                                          \
    __builtin_amdgcn_s_setprio(1);                                             \
    MFMAQ(1, 1);                                                               \
    __builtin_amdgcn_s_setprio(0);                                             \
    if ((MODE) == 0) asm volatile("s_waitcnt vmcnt(8)" ::: "memory");          \
    if ((MODE) == 1) asm volatile("s_waitcnt vmcnt(0)" ::: "memory");          \
    asm volatile("s_barrier" ::: "memory"); /* next tile's data landed */      \
  }

template <typename OUT_T>
__global__ __launch_bounds__(512, 2) void gemm256(const unsigned short* __restrict__ A,
                                                  const unsigned short* __restrict__ B,
                                                  OUT_T* __restrict__ C,
                                                  long Astride_z, long Cstride_z, int N) {
  __shared__ unsigned short lds[65536];   // 128 KiB
  const int tid = threadIdx.x;
  const int bn = blockIdx.x, bm = blockIdx.y, bz = blockIdx.z;
  const unsigned short* Ag = A + (long)bz * Astride_z + (long)bm * 256 * 4096;
  const unsigned short* Bg = B + (long)bn * 256 * 4096;

  const int w = tid >> 6, lane = tid & 63;
  const int wm = w >> 2, wn = w & 3;
  const int fr = lane & 15, fg = lane >> 4;
  // read slot = (kk*4+fg) ^ (fr&7); row-within-frag = fr
  const int ao0 = fr * 64 + ((fg ^ (fr & 7)) * 8);
  const int ao1 = fr * 64 + (((4 + fg) ^ (fr & 7)) * 8);
  // staging: thread writes LDS (row = j*64 + tid>>3, slot = tid&7);
  // global chunk for that slot = (tid&7) ^ (row&7)
  const int srow = tid >> 3;
  const int sslot = (tid & 7) ^ (srow & 7);

  f32x4 acc[8][4] = {};
  bf16x8 a[4][2], b[4][2];

  // prologue: stage tile 0 (parity 0) then tile 1 (parity 1); wait tile 0
  STG2(Ag, lds + 0, 0, 0);     STG2(Ag, lds + 16384, 1, 0);
  STG2(Bg, lds + 32768, 0, 0); STG2(Bg, lds + 49152, 1, 0);
  STG2(Ag, lds + 8192, 0, 64);  STG2(Ag, lds + 24576, 1, 64);
  STG2(Bg, lds + 40960, 0, 64); STG2(Bg, lds + 57344, 1, 64);
  asm volatile("s_waitcnt vmcnt(8)" ::: "memory");
  asm volatile("s_barrier" ::: "memory");

  for (int ti = 0; ti < 31; ++ti) {        // tiles 0..61
    TILE(0, (2 * ti + 2) * 64, 0);
    TILE(1, (2 * ti + 3) * 64, 0);
  }
  TILE(0, 0, 1);                           // tile 62: drain for tile 63
  TILE(1, 0, 2);                           // tile 63

  // epilogue: C row = wm*128 + mf*16 + fg*4 + rr, col = wn*64 + nf*16 + fr
  OUT_T* Cb = C + (long)bz * Cstride_z + ((long)bm * 256) * N + bn * 256;
#pragma unroll
  for (int mf = 0; mf < 8; ++mf)
#pragma unroll
    for (int nf = 0; nf < 4; ++nf)
#pragma unroll
      for (int rr = 0; rr < 4; ++rr) {
        int row = wm * 128 + mf * 16 + fg * 4 + rr;
        int col = wn * 64 + nf * 16 + fr;
        storeC(Cb + (long)row * N + col, acc[mf][nf][rr]);
      }
}

// ---- flash attention (round-2 structure: gload_lds staged, exp2, defer-max) ----
__global__ __launch_bounds__(256) void attn_fwd(const unsigned short* __restrict__ qb,
                                                const unsigned short* __restrict__ kb,
                                                const unsigned short* __restrict__ vT,
                                                unsigned short* __restrict__ ob) {
  __shared__ unsigned short Ks[64 * 128];
  __shared__ unsigned short Vl[128 * 64];
  __shared__ unsigned short Ps[4][16 * 72];

  const int qt = blockIdx.x, h = blockIdx.y, b = blockIdx.z;
  const int tid = threadIdx.x, w = tid >> 6, lane = tid & 63;
  const int fr = lane & 15, fg = lane >> 4;

  const unsigned short* kbase = kb + (long)b * 4096 * 4096 + h * 128;
  const unsigned short* vbase = vT + (long)h * 128 * 8192 + (long)b * 4096;

  bf16x8 qf[4];
  {
    const unsigned short* qptr =
        qb + ((long)b * 1024 + qt * 64 + w * 16 + fr) * 4096 + h * 128 + fg * 8;
#pragma unroll
    for (int c = 0; c < 4; c++) qf[c] = *reinterpret_cast<const bf16x8*>(qptr + c * 32);
  }

  f32x4 outa[8] = {};
  float m_run[4], l_run[4];
#pragma unroll
  for (int r = 0; r < 4; r++) { m_run[r] = -1e30f; l_run[r] = 0.0f; }

  for (int kv0 = 0; kv0 < 4096; kv0 += 64) {
    __syncthreads();
#pragma unroll
    for (int i = 0; i < 4; i++) {
      int c = tid + 256 * i;
      int key = c >> 4, s = c & 15;
      int Lg = s ^ (key & 15);
      load_lds16(kbase + (long)(kv0 + key) * 4096 + Lg * 8, Ks + c * 8);
    }
#pragma unroll
    for (int i = 0; i < 4; i++) {
      int c = tid + 256 * i;
      int f = c >> 3, s = c & 7;
      int Lg = s ^ (f & 7);
      load_lds16(vbase + (long)f * 8192 + kv0 + Lg * 8, Vl + c * 8);
    }
    __syncthreads();

    f32x4 sacc[4];
#pragma unroll
    for (int ks = 0; ks < 4; ks++) {
      f32x4 aq = {0.f, 0.f, 0.f, 0.f};
#pragma unroll
      for (int cc = 0; cc < 4; cc++) {
        bf16x8 kf = *reinterpret_cast<const bf16x8*>(
            &Ks[(ks * 16 + fr) * 128 + (((cc * 4 + fg) ^ fr) & 15) * 8]);
        aq = __builtin_amdgcn_mfma_f32_16x16x32_bf16(qf[cc], kf, aq, 0, 0, 0);
      }
      sacc[ks] = aq;
    }

    float mx4[4];
#pragma unroll
    for (int r = 0; r < 4; r++) {
      float mx = fmaxf(fmaxf(sacc[0][r], sacc[1][r]), fmaxf(sacc[2][r], sacc[3][r]));
      mx = fmaxf(mx, __shfl_xor(mx, 1));
      mx = fmaxf(mx, __shfl_xor(mx, 2));
      mx = fmaxf(mx, __shfl_xor(mx, 4));
      mx = fmaxf(mx, __shfl_xor(mx, 8));
      mx4[r] = mx;
    }
    int need = 0;
#pragma unroll
    for (int r = 0; r < 4; r++) need |= (mx4[r] > m_run[r] + 11.5f) ? 1 : 0;
    if (__any(need)) {
#pragma unroll
      for (int r = 0; r < 4; r++) {
        float mnew = fmaxf(m_run[r], mx4[r]);
        float ef = exp2f(m_run[r] - mnew);
        l_run[r] *= ef;
        m_run[r] = mnew;
#pragma unroll
        for (int ds = 0; ds < 8; ds++) outa[ds][r] *= ef;
      }
    }
    float p[4][4];
#pragma unroll
    for (int r = 0; r < 4; r++) {
      float sum = 0.f;
#pragma unroll
      for (int ks = 0; ks < 4; ks++) {
        float pv = exp2f(sacc[ks][r] - m_run[r]);
        p[ks][r] = pv;
        sum += pv;
      }
      sum += __shfl_xor(sum, 1);
      sum += __shfl_xor(sum, 2);
      sum += __shfl_xor(sum, 4);
      sum += __shfl_xor(sum, 8);
      l_run[r] += sum;
    }

#pragma unroll
    for (int r = 0; r < 4; r++)
#pragma unroll
      for (int ks = 0; ks < 4; ks++)
        Ps[w][(fg * 4 + r) * 72 + ks * 16 + fr] = f32_to_bf16_bits(p[ks][r]);

#pragma unroll
    for (int c2 = 0; c2 < 2; c2++) {
      bf16x8 pf = *reinterpret_cast<const bf16x8*>(&Ps[w][fr * 72 + c2 * 32 + fg * 8]);
#pragma unroll
      for (int ds = 0; ds < 8; ds++) {
        int feat = ds * 16 + fr;
        int pch = ((c2 * 4 + fg) ^ (feat & 7)) & 7;
        bf16x8 vf = *reinterpret_cast<const bf16x8*>(&Vl[feat * 64 + pch * 8]);
        outa[ds] = __builtin_amdgcn_mfma_f32_16x16x32_bf16(pf, vf, outa[ds], 0, 0, 0);
      }
    }
  }

#pragma unroll
  for (int r = 0; r < 4; r++) {
    float inv = 1.0f / l_run[r];
    unsigned short* op =
        ob + ((long)b * 1024 + qt * 64 + w * 16 + fg * 4 + r) * 4096 + h * 128;
#pragma unroll
    for (int ds = 0; ds < 8; ds++) op[ds * 16 + fr] = f32_to_bf16_bits(outa[ds][r] * inv);
  }
}

// ---------------------------------------------------------------------------
extern "C" void kernel_launch(void* const* d_in, const int* in_sizes, int n_in,
                              void* d_out, int out_size, void* d_ws, size_t ws_size,
                              hipStream_t stream) {
  const float* hs = (const float*)d_in[0];
  const float* wq = (const float*)d_in[1];
  const float* wk = (const float*)d_in[2];
  const float* wv = (const float*)d_in[3];
  const float* wo = (const float*)d_in[4];
  float* out = (float*)d_out;

  const long hsN = 2L * 4096 * 4096;
  const long wN  = 4096L * 4096;

  unsigned short* hs_b = (unsigned short*)d_ws;
  unsigned short* wq_b = hs_b + hsN;
  unsigned short* wk_b = wq_b + wN;
  unsigned short* wv_b = wk_b + wN;
  unsigned short* wo_b = wv_b + wN;
  unsigned short* q_b  = wo_b + wN;             // 2048 x 4096
  unsigned short* k_b  = q_b + 2048L * 4096;    // 8192 x 4096 ([tok][feat])
  unsigned short* vT_b = k_b + 8192L * 4096;    // 4096 x 8192 ([feat][tok])
  unsigned short* at_b = vT_b + 8192L * 4096;   // 2048 x 4096
  float* cos_t = (float*)(at_b + 2048L * 4096);
  float* sin_t = cos_t + 4096 * 64;

  cast_f32_bf16<<<dim3(4096), dim3(256), 0, stream>>>(hs, hs_b, hsN / 4);
  cast_f32_bf16<<<dim3(2048), dim3(256), 0, stream>>>(wq, wq_b, wN / 4);
  cast_f32_bf16<<<dim3(2048), dim3(256), 0, stream>>>(wk, wk_b, wN / 4);
  cast_f32_bf16<<<dim3(2048), dim3(256), 0, stream>>>(wv, wv_b, wN / 4);
  cast_f32_bf16<<<dim3(2048), dim3(256), 0, stream>>>(wo, wo_b, wN / 4);

  rope_tables<<<dim3(1024), dim3(256), 0, stream>>>(cos_t, sin_t);

  // Q[tok][feat] (2 batches of 1024 rows) — 128^2 kernel
  gemm_bt<unsigned short><<<dim3(32, 8, 2), dim3(256), 0, stream>>>(
      hs_b, wq_b, q_b, 4096L * 4096, 1024L * 4096, 4096);
  // K[tok][feat] — 256^2 pipelined
  gemm256<unsigned short><<<dim3(16, 16, 2), dim3(512), 0, stream>>>(
      hs_b, wk_b, k_b, 4096L * 4096, 4096L * 4096, 4096);
  // vT[feat][tok] = Wv * hs^T — 256^2 pipelined
  gemm256<unsigned short><<<dim3(32, 16, 1), dim3(512), 0, stream>>>(
      wv_b, hs_b, vT_b, 0L, 0L, 8192);

  const float qgain = 0.08838834764831845f * 1.4426950408889634f;
  rope_apply<<<dim3(16384), dim3(256), 0, stream>>>(q_b, cos_t, sin_t, 2048L * 2048, 1023, qgain);
  rope_apply<<<dim3(65536), dim3(256), 0, stream>>>(k_b, cos_t, sin_t, 8192L * 2048, 4095, 1.0f);

  attn_fwd<<<dim3(16, 32, 2), dim3(256), 0, stream>>>(q_b, k_b, vT_b, at_b);

  gemm_bt<float><<<dim3(32, 16, 1), dim3(256), 0, stream>>>(
      at_b, wo_b, out, 0L, 0L, 4096);
}